// Round 13
// baseline (226.863 us; speedup 1.0000x reference)
//
#include <hip/hip_runtime.h>
#include <stdint.h>

typedef unsigned int u32;
typedef uint8_t u8;
typedef uint16_t u16;
typedef __attribute__((ext_vector_type(8))) short bf16x8;
typedef __attribute__((ext_vector_type(4))) float f32x4;
typedef __attribute__((ext_vector_type(2))) float f32x2v;

#define EPSV 1e-12f
#define NB 256           // histogram blocks (1 per CU)
#define BINS_H 25600     // hist bins/pass (u16 packed LDS, 2 passes)
#define BINS_F 25600     // fill bins/pass (u16 packed LDS, 2 passes)

#if __has_builtin(__builtin_amdgcn_cvt_pk_f32_fp8) && \
    __has_builtin(__builtin_amdgcn_cvt_pk_fp8_f32)
#define FP8_HW 1
#endif

__device__ __forceinline__ u16 f2bf(float f) {
    u32 u = __float_as_uint(f);
    return (u16)((u + 0x7fffu + ((u >> 16) & 1u)) >> 16);
}
__device__ __forceinline__ float bf2f(u32 s) { return __uint_as_float(s << 16); }

// ---- fp8 e4m3 helpers ------------------------------------------------------
__device__ __forceinline__ float fp8_sw(u32 b) {
    int e = (b >> 3) & 0xf, m = b & 7;
    float v = e ? ldexpf((float)(8 + m), e - 10) : ldexpf((float)m, -9);
    return (b & 0x80) ? -v : v;
}
__device__ __forceinline__ u32 f2fp8_sw(float f) {
    u32 s = (__float_as_uint(f) >> 31) << 7;
    f = fabsf(f);
    if (f >= 448.f) return s | 0x7e;
    if (f < 0x1p-10f) return s;
    int ex; float mant = frexpf(f, &ex);
    int E = ex + 6;
    if (E >= 1) {
        int q = (int)rintf(mant * 16.f);
        if (q == 16) { q = 8; E += 1; }
        if (E > 15) return s | 0x7e;
        return s | ((u32)E << 3) | (u32)(q - 8);
    }
    int q = (int)rintf(f * 512.f);
    if (q > 7) return s | 0x08;
    return s | (u32)q;
}
// word-select operand must be an immediate -> two separate wrappers
__device__ __forceinline__ f32x2v fp8lo(u32 v) {
#ifdef FP8_HW
    return __builtin_amdgcn_cvt_pk_f32_fp8((int)v, false);
#else
    f32x2v r; r.x = fp8_sw(v & 0xff); r.y = fp8_sw((v >> 8) & 0xff);
    return r;
#endif
}
__device__ __forceinline__ f32x2v fp8hi(u32 v) {
#ifdef FP8_HW
    return __builtin_amdgcn_cvt_pk_f32_fp8((int)v, true);
#else
    u32 w = v >> 16;
    f32x2v r; r.x = fp8_sw(w & 0xff); r.y = fp8_sw((w >> 8) & 0xff);
    return r;
#endif
}
__device__ __forceinline__ u32 f2fp8(float f) {
#ifdef FP8_HW
    return (u32)__builtin_amdgcn_cvt_pk_fp8_f32(f, f, 0, false) & 0xffu;
#else
    return f2fp8_sw(f);
#endif
}
__device__ __forceinline__ u32 fp8pack2(float a, float b) {
    return f2fp8(a) | (f2fp8(b) << 8);
}

// ---------------------------------------------------------------------------
// K0: precompute transposed bf16 weights
// ---------------------------------------------------------------------------
__global__ __launch_bounds__(256) void k_prep(
    const float* __restrict__ W1, const float* __restrict__ W2,
    const float* __restrict__ Wup, u16* __restrict__ Wtc,
    u16* __restrict__ Wtu)
{
    int gid = blockIdx.x * 256 + threadIdx.x;
    if (gid < 32768) {
        int c = gid >> 7, k = gid & 127;
        float v = (c < 128) ? W1[k * 128 + c] : W2[k * 128 + (c - 128)];
        Wtc[gid] = f2bf(v);
    } else {
        int g = gid - 32768;      // c*256 + k
        int c = g >> 8, k = g & 255;
        Wtu[g] = f2bf(Wup[k * 128 + c]);
    }
}

// ---------------------------------------------------------------------------
// K1: edge MLP -> sigmoid weights (no atomics)
// ---------------------------------------------------------------------------
__global__ __launch_bounds__(256) void k_edge(
    const float* __restrict__ ea, const float* __restrict__ We1,
    const float* __restrict__ be1, const float* __restrict__ We2,
    const float* __restrict__ be2, float* __restrict__ ew, int E)
{
    __shared__ float w1t[32 * 16];
    __shared__ float b1s[32];
    __shared__ float w2s[32];
    __shared__ float b2s;
    int tid = threadIdx.x;
    for (int i = tid; i < 512; i += 256) {
        int k = i >> 5, j = i & 31;
        w1t[j * 16 + k] = We1[i];
    }
    if (tid < 32) { b1s[tid] = be1[tid]; w2s[tid] = We2[tid]; }
    if (tid == 0) b2s = be2[0];
    __syncthreads();

    int e = blockIdx.x * 256 + tid;
    if (e >= E) return;

    const float4* pa = (const float4*)(ea + (size_t)e * 16);
    float4 A0 = pa[0], A1 = pa[1], A2 = pa[2], A3 = pa[3];
    float av[16] = {A0.x, A0.y, A0.z, A0.w, A1.x, A1.y, A1.z, A1.w,
                    A2.x, A2.y, A2.z, A2.w, A3.x, A3.y, A3.z, A3.w};

    float acc = b2s;
#pragma unroll
    for (int j = 0; j < 32; ++j) {
        const float4* wr = (const float4*)(w1t + j * 16);
        float4 q0 = wr[0], q1 = wr[1], q2 = wr[2], q3 = wr[3];
        float s = b1s[j];
        s += av[0] * q0.x + av[1] * q0.y + av[2] * q0.z + av[3] * q0.w;
        s += av[4] * q1.x + av[5] * q1.y + av[6] * q1.z + av[7] * q1.w;
        s += av[8] * q2.x + av[9] * q2.y + av[10] * q2.z + av[11] * q2.w;
        s += av[12] * q3.x + av[13] * q3.y + av[14] * q3.z + av[15] * q3.w;
        acc += fmaxf(s, 0.f) * w2s[j];
    }
    ew[e] = 1.f / (1.f + __expf(-acc));
}

// ---------------------------------------------------------------------------
// K2: per-block LDS histograms; OUTPUT packed u16 (hb16[b][g] = counts of
//     rows 2g, 2g+1). Per-slice count <= 6250 fits u16.
// ---------------------------------------------------------------------------
__global__ __launch_bounds__(1024) void k_hist(
    const int* __restrict__ src, const int* __restrict__ dst,
    u32* __restrict__ hb16, int E, int n)
{
    __shared__ u32 h[BINS_H / 2];
    int b = blockIdx.x;
    int n2 = n >> 1;
    int E2 = 2 * E;
    int per = (E2 + NB - 1) / NB;
    int lo_e = b * per, hi_e = min(E2, lo_e + per);
    int npass = (n + BINS_H - 1) / BINS_H;

    for (int pass = 0; pass < npass; ++pass) {
        int lo = pass * BINS_H, hi = min(n, lo + BINS_H);
        for (int i = threadIdx.x; i < BINS_H / 2; i += 1024) h[i] = 0;
        __syncthreads();
        for (int idx = lo_e + threadIdx.x; idx < hi_e; idx += 1024) {
            int r = (idx < E) ? src[idx] : dst[idx - E];
            if (r >= lo && r < hi) {
                int rr = r - lo;
                atomicAdd(&h[rr >> 1], 1u << ((rr & 1) * 16));
            }
        }
        __syncthreads();
        int nw = (hi - lo + 1) >> 1;
        for (int i = threadIdx.x; i < nw; i += 1024)
            hb16[(size_t)b * n2 + (lo >> 1) + i] = h[i];
        __syncthreads();
    }
}

// ---------------------------------------------------------------------------
// K3: in-place packed exclusive prefix over blocks; emits per-row totals.
// ---------------------------------------------------------------------------
__global__ __launch_bounds__(256) void k_relscan(
    u32* __restrict__ hb16, int* __restrict__ tot, int n2)
{
    int g = blockIdx.x * 256 + threadIdx.x;
    if (g >= n2) return;
    u32 run = 0;
    for (int b = 0; b < NB; ++b) {
        u32 v = hb16[(size_t)b * n2 + g];
        hb16[(size_t)b * n2 + g] = run;
        run += v;                      // no cross-field carry: totals < 2^16
    }
    ((int2*)tot)[g] = make_int2((int)(run & 0xffffu), (int)(run >> 16));
}

// ---------------------------------------------------------------------------
// K4a: chunk sums (1024 elems/block; 256 thr x int4)
// ---------------------------------------------------------------------------
__global__ __launch_bounds__(256) void k_scan_a(
    const int* __restrict__ tot, int* __restrict__ bsum, int n)
{
    int tid = threadIdx.x, b = blockIdx.x;
    int i0 = b * 1024 + tid * 4;
    int s = 0;
    if (i0 + 3 < n) {
        int4 v = *(const int4*)(tot + i0);
        s = v.x + v.y + v.z + v.w;
    } else {
#pragma unroll
        for (int k = 0; k < 4; ++k) if (i0 + k < n) s += tot[i0 + k];
    }
#pragma unroll
    for (int d = 1; d < 64; d <<= 1) s += __shfl_xor(s, d);
    __shared__ int ws[4];
    if ((tid & 63) == 0) ws[tid >> 6] = s;
    __syncthreads();
    if (tid == 0) bsum[b] = ws[0] + ws[1] + ws[2] + ws[3];
}

// ---------------------------------------------------------------------------
// K4b: one-wave exclusive scan of chunk sums (nb <= 64, i.e. n <= 65536);
//      also writes rowptr[n] = grand total.
// ---------------------------------------------------------------------------
__global__ __launch_bounds__(64) void k_scan_b(
    const int* __restrict__ bsum, int* __restrict__ boff,
    int* __restrict__ rowptr, int nb, int n)
{
    int lane = threadIdx.x;
    int v = (lane < nb) ? bsum[lane] : 0;
    int p = v;
#pragma unroll
    for (int d = 1; d < 64; d <<= 1) {
        int t = __shfl_up(p, d);
        if (lane >= d) p += t;
    }
    if (lane < nb) boff[lane] = p - v;     // exclusive
    if (lane == 63) rowptr[n] = p;         // grand total
}

// ---------------------------------------------------------------------------
// K4c: per-chunk exclusive scan + chunk offset -> rowptr[0..n)
// ---------------------------------------------------------------------------
__global__ __launch_bounds__(256) void k_scan_c(
    const int* __restrict__ tot, const int* __restrict__ boff,
    int* __restrict__ rowptr, int n)
{
    int tid = threadIdx.x, b = blockIdx.x;
    int lane = tid & 63, w = tid >> 6;
    int i0 = b * 1024 + tid * 4;
    int v0 = 0, v1 = 0, v2 = 0, v3 = 0;
    if (i0 + 3 < n) {
        int4 t4 = *(const int4*)(tot + i0);
        v0 = t4.x; v1 = t4.y; v2 = t4.z; v3 = t4.w;
    } else {
        if (i0 < n)     v0 = tot[i0];
        if (i0 + 1 < n) v1 = tot[i0 + 1];
        if (i0 + 2 < n) v2 = tot[i0 + 2];
    }
    int t = v0 + v1 + v2 + v3;
    int p = t;
#pragma unroll
    for (int d = 1; d < 64; d <<= 1) {
        int u = __shfl_up(p, d);
        if (lane >= d) p += u;
    }
    int texc = p - t;                      // exclusive within wave
    __shared__ int ws[4];
    if (lane == 63) ws[w] = p;             // wave total
    __syncthreads();
    int woff = 0;
#pragma unroll
    for (int k = 0; k < 4; ++k) woff += (k < w) ? ws[k] : 0;
    int base = boff[b] + woff + texc;
    int e1 = base + v0, e2 = e1 + v1, e3 = e2 + v2;
    if (i0 + 3 < n) {
        *(int4*)(rowptr + i0) = make_int4(base, e1, e2, e3);
    } else {
        if (i0 < n)     rowptr[i0] = base;
        if (i0 + 1 < n) rowptr[i0 + 1] = e1;
        if (i0 + 2 < n) rowptr[i0 + 2] = e2;
    }
}

// ---------------------------------------------------------------------------
// K5: fill CSR. pos = rowptr[r] + u16 relative offset (LDS packed atomic).
//     cva[p] = col<<16 | q16(ew)   (col < 65536; ew in [0,1])
// ---------------------------------------------------------------------------
__global__ __launch_bounds__(1024) void k_fill(
    const int* __restrict__ src, const int* __restrict__ dst,
    const float* __restrict__ ew, const u32* __restrict__ hb16,
    const int* __restrict__ rowptr, u32* __restrict__ cva, int E, int n)
{
    __shared__ u32 rel[BINS_F / 2];
    int b = blockIdx.x;
    int n2 = n >> 1;
    int E2 = 2 * E;
    int per = (E2 + NB - 1) / NB;
    int lo_e = b * per, hi_e = min(E2, lo_e + per);
    int npass = (n + BINS_F - 1) / BINS_F;

    for (int pass = 0; pass < npass; ++pass) {
        int lo = pass * BINS_F, hi = min(n, lo + BINS_F);
        int nw = (hi - lo + 1) >> 1;
        for (int i = threadIdx.x; i < nw; i += 1024)
            rel[i] = hb16[(size_t)b * n2 + (lo >> 1) + i];
        __syncthreads();
        for (int idx = lo_e + threadIdx.x; idx < hi_e; idx += 1024) {
            int e = (idx < E) ? idx : idx - E;
            int r, c;
            if (idx < E) { r = src[e]; c = dst[e]; }
            else         { r = dst[e]; c = src[e]; }
            if (r >= lo && r < hi) {
                int rr = r - lo;
                u32 old = atomicAdd(&rel[rr >> 1], 1u << ((rr & 1) * 16));
                int off = (int)((old >> ((rr & 1) * 16)) & 0xffffu);
                u32 q = (u32)rintf(ew[e] * 65535.f);
                cva[rowptr[r] + off] = ((u32)c << 16) | q;
            }
        }
        __syncthreads();
    }
}

// ---------------------------------------------------------------------------
// K6: deg (q16 ew row sums) -> dinv (wave per row)
// ---------------------------------------------------------------------------
__global__ __launch_bounds__(256) void k_deg(
    const int* __restrict__ rowptr, const u32* __restrict__ cva,
    float* __restrict__ dinv, int n)
{
    int lane = threadIdx.x & 63;
    int row = blockIdx.x * 4 + (threadIdx.x >> 6);
    if (row >= n) return;
    int s = rowptr[row], e = rowptr[row + 1];
    float sum = 0.f;
    for (int p = s + lane; p < e; p += 64)
        sum += (float)(cva[p] & 0xffffu);
#pragma unroll
    for (int d = 1; d < 64; d <<= 1) sum += __shfl_xor(sum, d);
    if (lane == 0) dinv[row] = rsqrtf(sum * (1.f / 65535.f) + EPSV);
}

// ---------------------------------------------------------------------------
// K7: gemm1 via MFMA bf16, 32-row tiles (2x grid vs before, 6 blocks/CU).
//     Writes X1' = dinv⊙(H@W1) bf16 and X2' = dinv⊙(H@W2) fp8 e4m3.
//     B-fragments (Wtc, L2-hot) hoisted before the barrier.
// ---------------------------------------------------------------------------
__global__ __launch_bounds__(256) void k_gemm1(
    const float* __restrict__ H, const u16* __restrict__ Wtc,
    const float* __restrict__ dinv, u16* __restrict__ X1b,
    u8* __restrict__ X2q, int n)
{
    __shared__ __align__(16) u16 Asm[32 * 128];
    int tid = threadIdx.x;
    int r0blk = blockIdx.x * 32;
    int wv = tid >> 6, lane = tid & 63;
    int l15 = lane & 15, lg = lane >> 4;
    const u16* Wb = Wtc + (size_t)(wv * 64) * 128;

    // hoist all B fragments (16 x 16B, L2-resident) before staging drain
    bf16x8 bfr[4][4];
#pragma unroll
    for (int ks = 0; ks < 4; ++ks)
#pragma unroll
        for (int nt = 0; nt < 4; ++nt)
            bfr[ks][nt] = *(const bf16x8*)(Wb + (size_t)(nt * 16 + l15) * 128 +
                                           ks * 32 + lg * 8);

#pragma unroll
    for (int it = 0; it < 2; ++it) {
        int sidx = tid + it * 256;           // 32 rows x 16 slots
        int row = sidx >> 4, slot = sidx & 15;
        int gi = r0blk + row;
        float4 f0 = make_float4(0.f, 0.f, 0.f, 0.f), f1 = f0;
        if (gi < n) {
            const float4* p = (const float4*)(H + (size_t)gi * 128 + slot * 8);
            f0 = p[0]; f1 = p[1];
        }
        uint4 w;
        w.x = f2bf(f0.x) | ((u32)f2bf(f0.y) << 16);
        w.y = f2bf(f0.z) | ((u32)f2bf(f0.w) << 16);
        w.z = f2bf(f1.x) | ((u32)f2bf(f1.y) << 16);
        w.w = f2bf(f1.z) | ((u32)f2bf(f1.w) << 16);
        ((uint4*)Asm)[row * 16 + (slot ^ (row & 7))] = w;
    }
    __syncthreads();

    f32x4 acc[2][4] = {};
#pragma unroll
    for (int ks = 0; ks < 4; ++ks) {
        bf16x8 afr[2];
#pragma unroll
        for (int mt = 0; mt < 2; ++mt) {
            int row = mt * 16 + l15;
            int slot = ks * 4 + lg;
            afr[mt] = *(const bf16x8*)(Asm + row * 128 + (slot ^ (row & 7)) * 8);
        }
#pragma unroll
        for (int mt = 0; mt < 2; ++mt)
#pragma unroll
            for (int nt = 0; nt < 4; ++nt)
                acc[mt][nt] = __builtin_amdgcn_mfma_f32_16x16x32_bf16(
                    afr[mt], bfr[ks][nt], acc[mt][nt], 0, 0, 0);
    }

#pragma unroll
    for (int mt = 0; mt < 2; ++mt)
#pragma unroll
        for (int r = 0; r < 4; ++r) {
            int gi = r0blk + mt * 16 + lg * 4 + r;
            if (gi >= n) continue;
            float di = dinv[gi];
#pragma unroll
            for (int nt = 0; nt < 4; ++nt) {
                int col = wv * 64 + nt * 16 + l15;    // wave-uniform branch
                float v = acc[mt][nt][r] * di;
                if (col < 128)
                    X1b[(size_t)gi * 128 + col] = f2bf(v);
                else
                    X2q[(size_t)gi * 128 + (col - 128)] = (u8)f2fp8(v);
            }
        }
}

// ---------------------------------------------------------------------------
// K8: 128-col SpMM over fp8 gather table. Quarter-wave gather (16 lanes x
//     8B = one 128B row = one cache line), 4-deep pipeline, HW fp8 decode.
//   MIX: out(fp8) = gc * Xm[row] + (1-gc)*dinv^2 * (Ar @ Xq)[row]
//  !MIX: out(bf16) = (Ar @ Xq)[row]
// ---------------------------------------------------------------------------
template <bool MIX>
__global__ __launch_bounds__(256) void k_spmm(
    const int* __restrict__ rowptr, const u32* __restrict__ cva,
    const u8* __restrict__ Xq, const u16* __restrict__ Xm,
    void* __restrict__ outp, const float* __restrict__ gp,
    const float* __restrict__ dinv, int n)
{
    int lane = threadIdx.x & 63;
    int q = lane >> 4, l16 = lane & 15;
    int row = blockIdx.x * 4 + (threadIdx.x >> 6);
    if (row >= n) return;
    int s = rowptr[row], e = rowptr[row + 1];
    float a[8] = {0.f, 0.f, 0.f, 0.f, 0.f, 0.f, 0.f, 0.f};

#define GATHER(DD, WW, JJ)                                                   \
    {                                                                        \
        u32 v = __shfl(cv, (JJ));                                            \
        WW = (float)(v & 0xffffu) * (1.f / 65535.f);                         \
        DD = *(const uint2*)(Xq + (size_t)(v >> 16) * 128 + l16 * 8);        \
    }
#define ACC8(DD, WW)                                                         \
    {                                                                        \
        f32x2v p0 = fp8lo(DD.x), p1 = fp8hi(DD.x);                           \
        f32x2v p2 = fp8lo(DD.y), p3 = fp8hi(DD.y);                           \
        a[0] += WW * p0.x; a[1] += WW * p0.y;                                \
        a[2] += WW * p1.x; a[3] += WW * p1.y;                                \
        a[4] += WW * p2.x; a[5] += WW * p2.y;                                \
        a[6] += WW * p3.x; a[7] += WW * p3.y;                                \
    }

    for (int base = s; base < e; base += 64) {
        int p = base + lane;
        u32 cv = (p < e) ? cva[p] : 0u;       // q16=0 -> weight 0
        int m = min(64, e - base);
        for (int j0 = 0; j0 < m; j0 += 16) {
            uint2 d0, d1, d2, d3;
            float w0, w1, w2, w3;
            GATHER(d0, w0, j0 + q)
            GATHER(d1, w1, j0 + 4 + q)
            GATHER(d2, w2, j0 + 8 + q)
            GATHER(d3, w3, j0 + 12 + q)
            ACC8(d0, w0) ACC8(d1, w1) ACC8(d2, w2) ACC8(d3, w3)
        }
    }
#undef GATHER
#undef ACC8

#pragma unroll
    for (int k = 0; k < 8; ++k) {
        a[k] += __shfl_xor(a[k], 16);
        a[k] += __shfl_xor(a[k], 32);
    }
    if (q == 0) {
        if (MIX) {
            float gc = fminf(fmaxf(gp[0], 0.f), 1.f);
            float di = dinv[row];
            float sc = (1.f - gc) * di * di;
            uint4 x1 = *(const uint4*)(Xm + (size_t)row * 128 + l16 * 8);
            a[0] = gc * bf2f(x1.x & 0xffffu) + sc * a[0];
            a[1] = gc * bf2f(x1.x >> 16)     + sc * a[1];
            a[2] = gc * bf2f(x1.y & 0xffffu) + sc * a[2];
            a[3] = gc * bf2f(x1.y >> 16)     + sc * a[3];
            a[4] = gc * bf2f(x1.z & 0xffffu) + sc * a[4];
            a[5] = gc * bf2f(x1.z >> 16)     + sc * a[5];
            a[6] = gc * bf2f(x1.w & 0xffffu) + sc * a[6];
            a[7] = gc * bf2f(x1.w >> 16)     + sc * a[7];
            uint2 o;
            o.x = fp8pack2(a[0], a[1]) | (fp8pack2(a[2], a[3]) << 16);
            o.y = fp8pack2(a[4], a[5]) | (fp8pack2(a[6], a[7]) << 16);
            *(uint2*)((u8*)outp + (size_t)row * 128 + l16 * 8) = o;
        } else {
            uint4 o;
            o.x = f2bf(a[0]) | ((u32)f2bf(a[1]) << 16);
            o.y = f2bf(a[2]) | ((u32)f2bf(a[3]) << 16);
            o.z = f2bf(a[4]) | ((u32)f2bf(a[5]) << 16);
            o.w = f2bf(a[6]) | ((u32)f2bf(a[7]) << 16);
            *(uint4*)((u16*)outp + (size_t)row * 128 + l16 * 8) = o;
        }
    }
}

// ---------------------------------------------------------------------------
// K9: out = relu([dinv⊙agg, H] @ W_up + b_up) via MFMA bf16, 32-row tiles.
// ---------------------------------------------------------------------------
__global__ __launch_bounds__(256) void k_final(
    const u16* __restrict__ aggb, const float* __restrict__ H,
    const u16* __restrict__ Wtu, const float* __restrict__ bup,
    const float* __restrict__ dinv, float* __restrict__ out, int n)
{
    __shared__ __align__(16) u16 Asm[32 * 256];
    int tid = threadIdx.x;
    int r0blk = blockIdx.x * 32;

#pragma unroll
    for (int it = 0; it < 4; ++it) {
        int sidx = tid + it * 256;           // 32 rows x 32 slots
        int row = sidx >> 5, slot = sidx & 31;
        int gi = r0blk + row;
        uint4 w = make_uint4(0u, 0u, 0u, 0u);
        if (gi < n) {
            if (slot < 16) {
                uint4 y = *(const uint4*)(aggb + (size_t)gi * 128 + slot * 8);
                float di = dinv[gi];
                u32 ww[4] = {y.x, y.y, y.z, y.w};
#pragma unroll
                for (int q2 = 0; q2 < 4; ++q2) {
                    float a0 = bf2f(ww[q2] & 0xffffu) * di;
                    float a1 = bf2f(ww[q2] >> 16) * di;
                    ww[q2] = f2bf(a0) | ((u32)f2bf(a1) << 16);
                }
                w = make_uint4(ww[0], ww[1], ww[2], ww[3]);
            } else {
                const float4* p = (const float4*)(H + (size_t)gi * 128 + (slot - 16) * 8);
                float4 f0 = p[0], f1 = p[1];
                w.x = f2bf(f0.x) | ((u32)f2bf(f0.y) << 16);
                w.y = f2bf(f0.z) | ((u32)f2bf(f0.w) << 16);
                w.z = f2bf(f1.x) | ((u32)f2bf(f1.y) << 16);
                w.w = f2bf(f1.z) | ((u32)f2bf(f1.w) << 16);
            }
        }
        int grp = slot >> 3, sub = slot & 7;
        ((uint4*)Asm)[row * 32 + grp * 8 + (sub ^ (row & 7))] = w;
    }
    __syncthreads();

    int wv = tid >> 6, lane = tid & 63;
    int l15 = lane & 15, lg = lane >> 4;
    f32x4 acc[2][2] = {};
    const u16* Wb = Wtu + (size_t)(wv * 32) * 256;

#pragma unroll
    for (int ks = 0; ks < 8; ++ks) {
        bf16x8 bfr[2];
#pragma unroll
        for (int nt = 0; nt < 2; ++nt)
            bfr[nt] = *(const bf16x8*)(Wb + (size_t)(nt * 16 + l15) * 256 +
                                       ks * 32 + lg * 8);
        bf16x8 afr[2];
#pragma unroll
        for (int mt = 0; mt < 2; ++mt) {
            int row = mt * 16 + l15;
            int slot = ks * 4 + lg;
            int grp = slot >> 3, sub = slot & 7;
            afr[mt] = *(const bf16x8*)(Asm + row * 256 +
                                       (grp * 8 + (sub ^ (row & 7))) * 8);
        }
#pragma unroll
        for (int mt = 0; mt < 2; ++mt)
#pragma unroll
            for (int nt = 0; nt < 2; ++nt)
                acc[mt][nt] = __builtin_amdgcn_mfma_f32_16x16x32_bf16(
                    afr[mt], bfr[nt], acc[mt][nt], 0, 0, 0);
    }

#pragma unroll
    for (int mt = 0; mt < 2; ++mt)
#pragma unroll
        for (int r = 0; r < 4; ++r) {
            int gi = r0blk + mt * 16 + lg * 4 + r;
            if (gi >= n) continue;
#pragma unroll
            for (int nt = 0; nt < 2; ++nt) {
                int col = wv * 32 + nt * 16 + l15;
                float v = acc[mt][nt][r] + bup[col];
                out[(size_t)gi * 128 + col] = fmaxf(v, 0.f);
            }
        }
}

// ---------------------------------------------------------------------------
extern "C" void kernel_launch(void* const* d_in, const int* in_sizes, int n_in,
                              void* d_out, int out_size, void* d_ws,
                              size_t ws_size, hipStream_t stream)
{
    (void)n_in; (void)out_size; (void)ws_size;
    const float* H   = (const float*)d_in[0];
    const int*   ei  = (const int*)d_in[1];
    const float* ea  = (const float*)d_in[2];
    const float* W1  = (const float*)d_in[3];
    const float* W2  = (const float*)d_in[4];
    const float* We1 = (const float*)d_in[5];
    const float* be1 = (const float*)d_in[6];
    const float* We2 = (const float*)d_in[7];
    const float* be2 = (const float*)d_in[8];
    const float* g   = (const float*)d_in[9];
    const float* Wup = (const float*)d_in[10];
    const float* bup = (const float*)d_in[11];

    int n = in_sizes[0] / 128;     // 50000 (even; <=65536 for k_scan_b)
    int E = in_sizes[1] / 2;
    const int* src = ei;
    const int* dst = ei + E;
    float* out = (float*)d_out;

    char* wsp = (char*)d_ws;
    auto alloc = [&](size_t bytes) -> char* {
        char* p = wsp;
        wsp += (bytes + 255) & ~(size_t)255;
        return p;
    };
    float* ew     = (float*)alloc((size_t)E * 4);
    int*   tot    = (int*)alloc((size_t)n * 4);
    int*   rowptr = (int*)alloc((size_t)(n + 1) * 4);
    float* dinv   = (float*)alloc((size_t)n * 4);
    u32*   cva    = (u32*)alloc((size_t)2 * E * 4);     // col<<16 | q16(ew)
    u16*   Wtc    = (u16*)alloc((size_t)256 * 128 * 2);
    u16*   Wtu    = (u16*)alloc((size_t)128 * 256 * 2);
    u16*   X1b    = (u16*)alloc((size_t)n * 128 * 2);   // 12.8e6 B
    u8*    X2q    = (u8*)alloc((size_t)n * 128);        //  6.4e6 B
    u8*    Zq     = (u8*)alloc((size_t)n * 128);        //  6.4e6 B
    u16*   aggb   = (u16*)alloc((size_t)n * 128 * 2);
    int*   bsum   = (int*)alloc(64 * 4);
    int*   boff   = (int*)alloc(64 * 4);
    // hb16 = NB*(n/2)*4 = 256*25000*4 = 25.6e6 B aliases [X1b|X2q|Zq]
    // (12.8e6+6.4e6+6.4e6 = 25.6e6 EXACT; each size %256==0 so contiguous).
    // Lifetime hist..fill, all three targets written only after k_fill.
    // cva/bsum/boff NOT aliased (R6 lesson).
    u32*   hb16   = (u32*)X1b;

    int nb = (n + 1023) / 1024;    // 49 <= 64

    k_prep<<<256, 256, 0, stream>>>(W1, W2, Wup, Wtc, Wtu);
    k_edge<<<(E + 255) / 256, 256, 0, stream>>>(ea, We1, be1, We2, be2, ew, E);
    k_hist<<<NB, 1024, 0, stream>>>(src, dst, hb16, E, n);
    k_relscan<<<(n / 2 + 255) / 256, 256, 0, stream>>>(hb16, tot, n / 2);
    k_scan_a<<<nb, 256, 0, stream>>>(tot, bsum, n);
    k_scan_b<<<1, 64, 0, stream>>>(bsum, boff, rowptr, nb, n);
    k_scan_c<<<nb, 256, 0, stream>>>(tot, boff, rowptr, n);
    k_fill<<<NB, 1024, 0, stream>>>(src, dst, ew, hb16, rowptr, cva, E, n);
    k_deg<<<(n + 3) / 4, 256, 0, stream>>>(rowptr, cva, dinv, n);
    k_gemm1<<<(n + 31) / 32, 256, 0, stream>>>(H, Wtc, dinv, X1b, X2q, n);
    // u = Ar @ X2' ; Z' = gc*X1' + (1-gc)*dinv^2*u   (Z' stored fp8)
    k_spmm<true><<<(n + 3) / 4, 256, 0, stream>>>(rowptr, cva, X2q, X1b,
                                                  (void*)Zq, g, dinv, n);
    // v = Ar @ Z'   (aggb stored bf16)
    k_spmm<false><<<(n + 3) / 4, 256, 0, stream>>>(rowptr, cva, Zq, nullptr,
                                                   (void*)aggb, g, dinv, n);
    k_final<<<(n + 31) / 32, 256, 0, stream>>>(aggb, H, Wtu, bup, dinv, out, n);
}

// Round 14
// 203.185 us; speedup vs baseline: 1.1165x; 1.1165x over previous
//
#include <hip/hip_runtime.h>
#include <stdint.h>

typedef unsigned int u32;
typedef uint8_t u8;
typedef uint16_t u16;
typedef __attribute__((ext_vector_type(8))) short bf16x8;
typedef __attribute__((ext_vector_type(4))) float f32x4;
typedef __attribute__((ext_vector_type(2))) float f32x2v;

#define EPSV 1e-12f
#define NB 256           // histogram blocks (1 per CU)
#define NSEG 8           // relscan segments (NB/NSEG = 32 blocks each)
#define BINS_H 25600     // hist bins/pass (u16 packed LDS, 2 passes)
#define BINS_F 25600     // fill bins/pass (u16 packed LDS, 2 passes)

#if __has_builtin(__builtin_amdgcn_cvt_pk_f32_fp8) && \
    __has_builtin(__builtin_amdgcn_cvt_pk_fp8_f32)
#define FP8_HW 1
#endif

__device__ __forceinline__ u16 f2bf(float f) {
    u32 u = __float_as_uint(f);
    return (u16)((u + 0x7fffu + ((u >> 16) & 1u)) >> 16);
}
__device__ __forceinline__ float bf2f(u32 s) { return __uint_as_float(s << 16); }

// ---- fp8 e4m3 helpers ------------------------------------------------------
__device__ __forceinline__ float fp8_sw(u32 b) {
    int e = (b >> 3) & 0xf, m = b & 7;
    float v = e ? ldexpf((float)(8 + m), e - 10) : ldexpf((float)m, -9);
    return (b & 0x80) ? -v : v;
}
__device__ __forceinline__ u32 f2fp8_sw(float f) {
    u32 s = (__float_as_uint(f) >> 31) << 7;
    f = fabsf(f);
    if (f >= 448.f) return s | 0x7e;
    if (f < 0x1p-10f) return s;
    int ex; float mant = frexpf(f, &ex);
    int E = ex + 6;
    if (E >= 1) {
        int q = (int)rintf(mant * 16.f);
        if (q == 16) { q = 8; E += 1; }
        if (E > 15) return s | 0x7e;
        return s | ((u32)E << 3) | (u32)(q - 8);
    }
    int q = (int)rintf(f * 512.f);
    if (q > 7) return s | 0x08;
    return s | (u32)q;
}
// word-select operand must be an immediate -> two separate wrappers
__device__ __forceinline__ f32x2v fp8lo(u32 v) {
#ifdef FP8_HW
    return __builtin_amdgcn_cvt_pk_f32_fp8((int)v, false);
#else
    f32x2v r; r.x = fp8_sw(v & 0xff); r.y = fp8_sw((v >> 8) & 0xff);
    return r;
#endif
}
__device__ __forceinline__ f32x2v fp8hi(u32 v) {
#ifdef FP8_HW
    return __builtin_amdgcn_cvt_pk_f32_fp8((int)v, true);
#else
    u32 w = v >> 16;
    f32x2v r; r.x = fp8_sw(w & 0xff); r.y = fp8_sw((w >> 8) & 0xff);
    return r;
#endif
}
__device__ __forceinline__ u32 f2fp8(float f) {
#ifdef FP8_HW
    return (u32)__builtin_amdgcn_cvt_pk_fp8_f32(f, f, 0, false) & 0xffu;
#else
    return f2fp8_sw(f);
#endif
}
__device__ __forceinline__ u32 fp8pack2(float a, float b) {
    return f2fp8(a) | (f2fp8(b) << 8);
}

// ---------------------------------------------------------------------------
// K0: precompute transposed bf16 weights
// ---------------------------------------------------------------------------
__global__ __launch_bounds__(256) void k_prep(
    const float* __restrict__ W1, const float* __restrict__ W2,
    const float* __restrict__ Wup, u16* __restrict__ Wtc,
    u16* __restrict__ Wtu)
{
    int gid = blockIdx.x * 256 + threadIdx.x;
    if (gid < 32768) {
        int c = gid >> 7, k = gid & 127;
        float v = (c < 128) ? W1[k * 128 + c] : W2[k * 128 + (c - 128)];
        Wtc[gid] = f2bf(v);
    } else {
        int g = gid - 32768;      // c*256 + k
        int c = g >> 8, k = g & 255;
        Wtu[g] = f2bf(Wup[k * 128 + c]);
    }
}

// ---------------------------------------------------------------------------
// K1: edge MLP -> sigmoid weights (no atomics)
// ---------------------------------------------------------------------------
__global__ __launch_bounds__(256) void k_edge(
    const float* __restrict__ ea, const float* __restrict__ We1,
    const float* __restrict__ be1, const float* __restrict__ We2,
    const float* __restrict__ be2, float* __restrict__ ew, int E)
{
    __shared__ float w1t[32 * 16];
    __shared__ float b1s[32];
    __shared__ float w2s[32];
    __shared__ float b2s;
    int tid = threadIdx.x;
    for (int i = tid; i < 512; i += 256) {
        int k = i >> 5, j = i & 31;
        w1t[j * 16 + k] = We1[i];
    }
    if (tid < 32) { b1s[tid] = be1[tid]; w2s[tid] = We2[tid]; }
    if (tid == 0) b2s = be2[0];
    __syncthreads();

    int e = blockIdx.x * 256 + tid;
    if (e >= E) return;

    const float4* pa = (const float4*)(ea + (size_t)e * 16);
    float4 A0 = pa[0], A1 = pa[1], A2 = pa[2], A3 = pa[3];
    float av[16] = {A0.x, A0.y, A0.z, A0.w, A1.x, A1.y, A1.z, A1.w,
                    A2.x, A2.y, A2.z, A2.w, A3.x, A3.y, A3.z, A3.w};

    float acc = b2s;
#pragma unroll
    for (int j = 0; j < 32; ++j) {
        const float4* wr = (const float4*)(w1t + j * 16);
        float4 q0 = wr[0], q1 = wr[1], q2 = wr[2], q3 = wr[3];
        float s = b1s[j];
        s += av[0] * q0.x + av[1] * q0.y + av[2] * q0.z + av[3] * q0.w;
        s += av[4] * q1.x + av[5] * q1.y + av[6] * q1.z + av[7] * q1.w;
        s += av[8] * q2.x + av[9] * q2.y + av[10] * q2.z + av[11] * q2.w;
        s += av[12] * q3.x + av[13] * q3.y + av[14] * q3.z + av[15] * q3.w;
        acc += fmaxf(s, 0.f) * w2s[j];
    }
    ew[e] = 1.f / (1.f + __expf(-acc));
}

// ---------------------------------------------------------------------------
// K2: per-block LDS histograms; OUTPUT packed u16 (hb16[b][g] = counts of
//     rows 2g, 2g+1). Per-slice count <= 6250 fits u16.
// ---------------------------------------------------------------------------
__global__ __launch_bounds__(1024) void k_hist(
    const int* __restrict__ src, const int* __restrict__ dst,
    u32* __restrict__ hb16, int E, int n)
{
    __shared__ u32 h[BINS_H / 2];
    int b = blockIdx.x;
    int n2 = n >> 1;
    int E2 = 2 * E;
    int per = (E2 + NB - 1) / NB;
    int lo_e = b * per, hi_e = min(E2, lo_e + per);
    int npass = (n + BINS_H - 1) / BINS_H;

    for (int pass = 0; pass < npass; ++pass) {
        int lo = pass * BINS_H, hi = min(n, lo + BINS_H);
        for (int i = threadIdx.x; i < BINS_H / 2; i += 1024) h[i] = 0;
        __syncthreads();
        for (int idx = lo_e + threadIdx.x; idx < hi_e; idx += 1024) {
            int r = (idx < E) ? src[idx] : dst[idx - E];
            if (r >= lo && r < hi) {
                int rr = r - lo;
                atomicAdd(&h[rr >> 1], 1u << ((rr & 1) * 16));
            }
        }
        __syncthreads();
        int nw = (hi - lo + 1) >> 1;
        for (int i = threadIdx.x; i < nw; i += 1024)
            hb16[(size_t)b * n2 + (lo >> 1) + i] = h[i];
        __syncthreads();
    }
}

// ---------------------------------------------------------------------------
// K3a: per-SEGMENT in-place packed exclusive prefix (32 blocks each);
//      emits packed segment sums. Grid: (gblks, NSEG).
// ---------------------------------------------------------------------------
__global__ __launch_bounds__(256) void k_relscan1(
    u32* __restrict__ hb16, u32* __restrict__ segsum, int n2)
{
    int g = blockIdx.x * 256 + threadIdx.x;
    if (g >= n2) return;
    int s = blockIdx.y;
    int b0 = s * (NB / NSEG);
    u32 run = 0;
    for (int b = b0; b < b0 + NB / NSEG; ++b) {
        u32 v = hb16[(size_t)b * n2 + g];
        hb16[(size_t)b * n2 + g] = run;
        run += v;                      // no cross-field carry: totals < 2^16
    }
    segsum[(size_t)s * n2 + g] = run;
}

// ---------------------------------------------------------------------------
// K3b: exclusive scan of NSEG segment sums in place (-> segoff); emits tot.
// ---------------------------------------------------------------------------
__global__ __launch_bounds__(256) void k_relscan2(
    u32* __restrict__ segsum, int* __restrict__ tot, int n2)
{
    int g = blockIdx.x * 256 + threadIdx.x;
    if (g >= n2) return;
    u32 run = 0;
#pragma unroll
    for (int s = 0; s < NSEG; ++s) {
        u32 v = segsum[(size_t)s * n2 + g];
        segsum[(size_t)s * n2 + g] = run;
        run += v;
    }
    ((int2*)tot)[g] = make_int2((int)(run & 0xffffu), (int)(run >> 16));
}

// ---------------------------------------------------------------------------
// K4a: chunk sums (1024 elems/block; 256 thr x int4)
// ---------------------------------------------------------------------------
__global__ __launch_bounds__(256) void k_scan_a(
    const int* __restrict__ tot, int* __restrict__ bsum, int n)
{
    int tid = threadIdx.x, b = blockIdx.x;
    int i0 = b * 1024 + tid * 4;
    int s = 0;
    if (i0 + 3 < n) {
        int4 v = *(const int4*)(tot + i0);
        s = v.x + v.y + v.z + v.w;
    } else {
#pragma unroll
        for (int k = 0; k < 4; ++k) if (i0 + k < n) s += tot[i0 + k];
    }
#pragma unroll
    for (int d = 1; d < 64; d <<= 1) s += __shfl_xor(s, d);
    __shared__ int ws[4];
    if ((tid & 63) == 0) ws[tid >> 6] = s;
    __syncthreads();
    if (tid == 0) bsum[b] = ws[0] + ws[1] + ws[2] + ws[3];
}

// ---------------------------------------------------------------------------
// K4b: one-wave exclusive scan of chunk sums (nb <= 64, i.e. n <= 65536);
//      also writes rowptr[n] = grand total.
// ---------------------------------------------------------------------------
__global__ __launch_bounds__(64) void k_scan_b(
    const int* __restrict__ bsum, int* __restrict__ boff,
    int* __restrict__ rowptr, int nb, int n)
{
    int lane = threadIdx.x;
    int v = (lane < nb) ? bsum[lane] : 0;
    int p = v;
#pragma unroll
    for (int d = 1; d < 64; d <<= 1) {
        int t = __shfl_up(p, d);
        if (lane >= d) p += t;
    }
    if (lane < nb) boff[lane] = p - v;     // exclusive
    if (lane == 63) rowptr[n] = p;         // grand total
}

// ---------------------------------------------------------------------------
// K4c: per-chunk exclusive scan + chunk offset -> rowptr[0..n)
// ---------------------------------------------------------------------------
__global__ __launch_bounds__(256) void k_scan_c(
    const int* __restrict__ tot, const int* __restrict__ boff,
    int* __restrict__ rowptr, int n)
{
    int tid = threadIdx.x, b = blockIdx.x;
    int lane = tid & 63, w = tid >> 6;
    int i0 = b * 1024 + tid * 4;
    int v0 = 0, v1 = 0, v2 = 0, v3 = 0;
    if (i0 + 3 < n) {
        int4 t4 = *(const int4*)(tot + i0);
        v0 = t4.x; v1 = t4.y; v2 = t4.z; v3 = t4.w;
    } else {
        if (i0 < n)     v0 = tot[i0];
        if (i0 + 1 < n) v1 = tot[i0 + 1];
        if (i0 + 2 < n) v2 = tot[i0 + 2];
    }
    int t = v0 + v1 + v2 + v3;
    int p = t;
#pragma unroll
    for (int d = 1; d < 64; d <<= 1) {
        int u = __shfl_up(p, d);
        if (lane >= d) p += u;
    }
    int texc = p - t;                      // exclusive within wave
    __shared__ int ws[4];
    if (lane == 63) ws[w] = p;             // wave total
    __syncthreads();
    int woff = 0;
#pragma unroll
    for (int k = 0; k < 4; ++k) woff += (k < w) ? ws[k] : 0;
    int base = boff[b] + woff + texc;
    int e1 = base + v0, e2 = e1 + v1, e3 = e2 + v2;
    if (i0 + 3 < n) {
        *(int4*)(rowptr + i0) = make_int4(base, e1, e2, e3);
    } else {
        if (i0 < n)     rowptr[i0] = base;
        if (i0 + 1 < n) rowptr[i0 + 1] = e1;
        if (i0 + 2 < n) rowptr[i0 + 2] = e2;
    }
}

// ---------------------------------------------------------------------------
// K5: fill CSR. pos = rowptr[r] + u16 relative offset (LDS packed atomic on
//     per-block segment-relative prefix + segment offset, packed add).
//     cva[p] = col<<16 | q16(ew)   (col < 65536; ew in [0,1])
// ---------------------------------------------------------------------------
__global__ __launch_bounds__(1024) void k_fill(
    const int* __restrict__ src, const int* __restrict__ dst,
    const float* __restrict__ ew, const u32* __restrict__ hb16,
    const u32* __restrict__ segoff, const int* __restrict__ rowptr,
    u32* __restrict__ cva, int E, int n)
{
    __shared__ u32 rel[BINS_F / 2];
    int b = blockIdx.x;
    int seg = b / (NB / NSEG);
    int n2 = n >> 1;
    int E2 = 2 * E;
    int per = (E2 + NB - 1) / NB;
    int lo_e = b * per, hi_e = min(E2, lo_e + per);
    int npass = (n + BINS_F - 1) / BINS_F;

    for (int pass = 0; pass < npass; ++pass) {
        int lo = pass * BINS_F, hi = min(n, lo + BINS_F);
        int nw = (hi - lo + 1) >> 1;
        for (int i = threadIdx.x; i < nw; i += 1024)
            rel[i] = hb16[(size_t)b * n2 + (lo >> 1) + i] +
                     segoff[(size_t)seg * n2 + (lo >> 1) + i];  // packed add
        __syncthreads();
        for (int idx = lo_e + threadIdx.x; idx < hi_e; idx += 1024) {
            int e = (idx < E) ? idx : idx - E;
            int r, c;
            if (idx < E) { r = src[e]; c = dst[e]; }
            else         { r = dst[e]; c = src[e]; }
            if (r >= lo && r < hi) {
                int rr = r - lo;
                u32 old = atomicAdd(&rel[rr >> 1], 1u << ((rr & 1) * 16));
                int off = (int)((old >> ((rr & 1) * 16)) & 0xffffu);
                u32 q = (u32)rintf(ew[e] * 65535.f);
                cva[rowptr[r] + off] = ((u32)c << 16) | q;
            }
        }
        __syncthreads();
    }
}

// ---------------------------------------------------------------------------
// K6: deg (q16 ew row sums) -> dinv (wave per row)
// ---------------------------------------------------------------------------
__global__ __launch_bounds__(256) void k_deg(
    const int* __restrict__ rowptr, const u32* __restrict__ cva,
    float* __restrict__ dinv, int n)
{
    int lane = threadIdx.x & 63;
    int row = blockIdx.x * 4 + (threadIdx.x >> 6);
    if (row >= n) return;
    int s = rowptr[row], e = rowptr[row + 1];
    float sum = 0.f;
    for (int p = s + lane; p < e; p += 64)
        sum += (float)(cva[p] & 0xffffu);
#pragma unroll
    for (int d = 1; d < 64; d <<= 1) sum += __shfl_xor(sum, d);
    if (lane == 0) dinv[row] = rsqrtf(sum * (1.f / 65535.f) + EPSV);
}

// ---------------------------------------------------------------------------
// K7: gemm1 via MFMA bf16, 32-row tiles. X1' bf16, X2' fp8 e4m3.
// ---------------------------------------------------------------------------
__global__ __launch_bounds__(256) void k_gemm1(
    const float* __restrict__ H, const u16* __restrict__ Wtc,
    const float* __restrict__ dinv, u16* __restrict__ X1b,
    u8* __restrict__ X2q, int n)
{
    __shared__ __align__(16) u16 Asm[32 * 128];
    int tid = threadIdx.x;
    int r0blk = blockIdx.x * 32;
    int wv = tid >> 6, lane = tid & 63;
    int l15 = lane & 15, lg = lane >> 4;
    const u16* Wb = Wtc + (size_t)(wv * 64) * 128;

    bf16x8 bfr[4][4];
#pragma unroll
    for (int ks = 0; ks < 4; ++ks)
#pragma unroll
        for (int nt = 0; nt < 4; ++nt)
            bfr[ks][nt] = *(const bf16x8*)(Wb + (size_t)(nt * 16 + l15) * 128 +
                                           ks * 32 + lg * 8);

#pragma unroll
    for (int it = 0; it < 2; ++it) {
        int sidx = tid + it * 256;           // 32 rows x 16 slots
        int row = sidx >> 4, slot = sidx & 15;
        int gi = r0blk + row;
        float4 f0 = make_float4(0.f, 0.f, 0.f, 0.f), f1 = f0;
        if (gi < n) {
            const float4* p = (const float4*)(H + (size_t)gi * 128 + slot * 8);
            f0 = p[0]; f1 = p[1];
        }
        uint4 w;
        w.x = f2bf(f0.x) | ((u32)f2bf(f0.y) << 16);
        w.y = f2bf(f0.z) | ((u32)f2bf(f0.w) << 16);
        w.z = f2bf(f1.x) | ((u32)f2bf(f1.y) << 16);
        w.w = f2bf(f1.z) | ((u32)f2bf(f1.w) << 16);
        ((uint4*)Asm)[row * 16 + (slot ^ (row & 7))] = w;
    }
    __syncthreads();

    f32x4 acc[2][4] = {};
#pragma unroll
    for (int ks = 0; ks < 4; ++ks) {
        bf16x8 afr[2];
#pragma unroll
        for (int mt = 0; mt < 2; ++mt) {
            int row = mt * 16 + l15;
            int slot = ks * 4 + lg;
            afr[mt] = *(const bf16x8*)(Asm + row * 128 + (slot ^ (row & 7)) * 8);
        }
#pragma unroll
        for (int mt = 0; mt < 2; ++mt)
#pragma unroll
            for (int nt = 0; nt < 4; ++nt)
                acc[mt][nt] = __builtin_amdgcn_mfma_f32_16x16x32_bf16(
                    afr[mt], bfr[ks][nt], acc[mt][nt], 0, 0, 0);
    }

#pragma unroll
    for (int mt = 0; mt < 2; ++mt)
#pragma unroll
        for (int r = 0; r < 4; ++r) {
            int gi = r0blk + mt * 16 + lg * 4 + r;
            if (gi >= n) continue;
            float di = dinv[gi];
#pragma unroll
            for (int nt = 0; nt < 4; ++nt) {
                int col = wv * 64 + nt * 16 + l15;    // wave-uniform branch
                float v = acc[mt][nt][r] * di;
                if (col < 128)
                    X1b[(size_t)gi * 128 + col] = f2bf(v);
                else
                    X2q[(size_t)gi * 128 + (col - 128)] = (u8)f2fp8(v);
            }
        }
}

// ---------------------------------------------------------------------------
// K8: 128-col SpMM over fp8 gather table. Quarter-wave gather, HW fp8 decode.
//   MIX: out(fp8) = gc * Xm[row] + (1-gc)*dinv^2 * (Ar @ Xq)[row]
//  !MIX: out(bf16) = (Ar @ Xq)[row]
// ---------------------------------------------------------------------------
template <bool MIX>
__global__ __launch_bounds__(256) void k_spmm(
    const int* __restrict__ rowptr, const u32* __restrict__ cva,
    const u8* __restrict__ Xq, const u16* __restrict__ Xm,
    void* __restrict__ outp, const float* __restrict__ gp,
    const float* __restrict__ dinv, int n)
{
    int lane = threadIdx.x & 63;
    int q = lane >> 4, l16 = lane & 15;
    int row = blockIdx.x * 4 + (threadIdx.x >> 6);
    if (row >= n) return;
    int s = rowptr[row], e = rowptr[row + 1];
    float a[8] = {0.f, 0.f, 0.f, 0.f, 0.f, 0.f, 0.f, 0.f};

#define GATHER(DD, WW, JJ)                                                   \
    {                                                                        \
        u32 v = __shfl(cv, (JJ));                                            \
        WW = (float)(v & 0xffffu) * (1.f / 65535.f);                         \
        DD = *(const uint2*)(Xq + (size_t)(v >> 16) * 128 + l16 * 8);        \
    }
#define ACC8(DD, WW)                                                         \
    {                                                                        \
        f32x2v p0 = fp8lo(DD.x), p1 = fp8hi(DD.x);                           \
        f32x2v p2 = fp8lo(DD.y), p3 = fp8hi(DD.y);                           \
        a[0] += WW * p0.x; a[1] += WW * p0.y;                                \
        a[2] += WW * p1.x; a[3] += WW * p1.y;                                \
        a[4] += WW * p2.x; a[5] += WW * p2.y;                                \
        a[6] += WW * p3.x; a[7] += WW * p3.y;                                \
    }

    for (int base = s; base < e; base += 64) {
        int p = base + lane;
        u32 cv = (p < e) ? cva[p] : 0u;       // q16=0 -> weight 0
        int m = min(64, e - base);
        for (int j0 = 0; j0 < m; j0 += 16) {
            uint2 d0, d1, d2, d3;
            float w0, w1, w2, w3;
            GATHER(d0, w0, j0 + q)
            GATHER(d1, w1, j0 + 4 + q)
            GATHER(d2, w2, j0 + 8 + q)
            GATHER(d3, w3, j0 + 12 + q)
            ACC8(d0, w0) ACC8(d1, w1) ACC8(d2, w2) ACC8(d3, w3)
        }
    }
#undef GATHER
#undef ACC8

#pragma unroll
    for (int k = 0; k < 8; ++k) {
        a[k] += __shfl_xor(a[k], 16);
        a[k] += __shfl_xor(a[k], 32);
    }
    if (q == 0) {
        if (MIX) {
            float gc = fminf(fmaxf(gp[0], 0.f), 1.f);
            float di = dinv[row];
            float sc = (1.f - gc) * di * di;
            uint4 x1 = *(const uint4*)(Xm + (size_t)row * 128 + l16 * 8);
            a[0] = gc * bf2f(x1.x & 0xffffu) + sc * a[0];
            a[1] = gc * bf2f(x1.x >> 16)     + sc * a[1];
            a[2] = gc * bf2f(x1.y & 0xffffu) + sc * a[2];
            a[3] = gc * bf2f(x1.y >> 16)     + sc * a[3];
            a[4] = gc * bf2f(x1.z & 0xffffu) + sc * a[4];
            a[5] = gc * bf2f(x1.z >> 16)     + sc * a[5];
            a[6] = gc * bf2f(x1.w & 0xffffu) + sc * a[6];
            a[7] = gc * bf2f(x1.w >> 16)     + sc * a[7];
            uint2 o;
            o.x = fp8pack2(a[0], a[1]) | (fp8pack2(a[2], a[3]) << 16);
            o.y = fp8pack2(a[4], a[5]) | (fp8pack2(a[6], a[7]) << 16);
            *(uint2*)((u8*)outp + (size_t)row * 128 + l16 * 8) = o;
        } else {
            uint4 o;
            o.x = f2bf(a[0]) | ((u32)f2bf(a[1]) << 16);
            o.y = f2bf(a[2]) | ((u32)f2bf(a[3]) << 16);
            o.z = f2bf(a[4]) | ((u32)f2bf(a[5]) << 16);
            o.w = f2bf(a[6]) | ((u32)f2bf(a[7]) << 16);
            *(uint4*)((u16*)outp + (size_t)row * 128 + l16 * 8) = o;
        }
    }
}

// ---------------------------------------------------------------------------
// K9: out = relu([dinv⊙agg, H] @ W_up + b_up) via MFMA bf16, 32-row tiles.
// ---------------------------------------------------------------------------
__global__ __launch_bounds__(256) void k_final(
    const u16* __restrict__ aggb, const float* __restrict__ H,
    const u16* __restrict__ Wtu, const float* __restrict__ bup,
    const float* __restrict__ dinv, float* __restrict__ out, int n)
{
    __shared__ __align__(16) u16 Asm[32 * 256];
    int tid = threadIdx.x;
    int r0blk = blockIdx.x * 32;

#pragma unroll
    for (int it = 0; it < 4; ++it) {
        int sidx = tid + it * 256;           // 32 rows x 32 slots
        int row = sidx >> 5, slot = sidx & 31;
        int gi = r0blk + row;
        uint4 w = make_uint4(0u, 0u, 0u, 0u);
        if (gi < n) {
            if (slot < 16) {
                uint4 y = *(const uint4*)(aggb + (size_t)gi * 128 + slot * 8);
                float di = dinv[gi];
                u32 ww[4] = {y.x, y.y, y.z, y.w};
#pragma unroll
                for (int q2 = 0; q2 < 4; ++q2) {
                    float a0 = bf2f(ww[q2] & 0xffffu) * di;
                    float a1 = bf2f(ww[q2] >> 16) * di;
                    ww[q2] = f2bf(a0) | ((u32)f2bf(a1) << 16);
                }
                w = make_uint4(ww[0], ww[1], ww[2], ww[3]);
            } else {
                const float4* p = (const float4*)(H + (size_t)gi * 128 + (slot - 16) * 8);
                float4 f0 = p[0], f1 = p[1];
                w.x = f2bf(f0.x) | ((u32)f2bf(f0.y) << 16);
                w.y = f2bf(f0.z) | ((u32)f2bf(f0.w) << 16);
                w.z = f2bf(f1.x) | ((u32)f2bf(f1.y) << 16);
                w.w = f2bf(f1.z) | ((u32)f2bf(f1.w) << 16);
            }
        }
        int grp = slot >> 3, sub = slot & 7;
        ((uint4*)Asm)[row * 32 + grp * 8 + (sub ^ (row & 7))] = w;
    }
    __syncthreads();

    int wv = tid >> 6, lane = tid & 63;
    int l15 = lane & 15, lg = lane >> 4;
    f32x4 acc[2][2] = {};
    const u16* Wb = Wtu + (size_t)(wv * 32) * 256;

#pragma unroll
    for (int ks = 0; ks < 8; ++ks) {
        bf16x8 bfr[2];
#pragma unroll
        for (int nt = 0; nt < 2; ++nt)
            bfr[nt] = *(const bf16x8*)(Wb + (size_t)(nt * 16 + l15) * 256 +
                                       ks * 32 + lg * 8);
        bf16x8 afr[2];
#pragma unroll
        for (int mt = 0; mt < 2; ++mt) {
            int row = mt * 16 + l15;
            int slot = ks * 4 + lg;
            int grp = slot >> 3, sub = slot & 7;
            afr[mt] = *(const bf16x8*)(Asm + row * 256 +
                                       (grp * 8 + (sub ^ (row & 7))) * 8);
        }
#pragma unroll
        for (int mt = 0; mt < 2; ++mt)
#pragma unroll
            for (int nt = 0; nt < 2; ++nt)
                acc[mt][nt] = __builtin_amdgcn_mfma_f32_16x16x32_bf16(
                    afr[mt], bfr[nt], acc[mt][nt], 0, 0, 0);
    }

#pragma unroll
    for (int mt = 0; mt < 2; ++mt)
#pragma unroll
        for (int r = 0; r < 4; ++r) {
            int gi = r0blk + mt * 16 + lg * 4 + r;
            if (gi >= n) continue;
#pragma unroll
            for (int nt = 0; nt < 2; ++nt) {
                int col = wv * 32 + nt * 16 + l15;
                float v = acc[mt][nt][r] + bup[col];
                out[(size_t)gi * 128 + col] = fmaxf(v, 0.f);
            }
        }
}

// ---------------------------------------------------------------------------
extern "C" void kernel_launch(void* const* d_in, const int* in_sizes, int n_in,
                              void* d_out, int out_size, void* d_ws,
                              size_t ws_size, hipStream_t stream)
{
    (void)n_in; (void)out_size; (void)ws_size;
    const float* H   = (const float*)d_in[0];
    const int*   ei  = (const int*)d_in[1];
    const float* ea  = (const float*)d_in[2];
    const float* W1  = (const float*)d_in[3];
    const float* W2  = (const float*)d_in[4];
    const float* We1 = (const float*)d_in[5];
    const float* be1 = (const float*)d_in[6];
    const float* We2 = (const float*)d_in[7];
    const float* be2 = (const float*)d_in[8];
    const float* g   = (const float*)d_in[9];
    const float* Wup = (const float*)d_in[10];
    const float* bup = (const float*)d_in[11];

    int n = in_sizes[0] / 128;     // 50000 (even; <=65536 for k_scan_b)
    int E = in_sizes[1] / 2;
    const int* src = ei;
    const int* dst = ei + E;
    float* out = (float*)d_out;

    char* wsp = (char*)d_ws;
    auto alloc = [&](size_t bytes) -> char* {
        char* p = wsp;
        wsp += (bytes + 255) & ~(size_t)255;
        return p;
    };
    float* ew     = (float*)alloc((size_t)E * 4);
    int*   tot    = (int*)alloc((size_t)n * 4);
    int*   rowptr = (int*)alloc((size_t)(n + 1) * 4);
    float* dinv   = (float*)alloc((size_t)n * 4);
    u32*   cva    = (u32*)alloc((size_t)2 * E * 4);     // col<<16 | q16(ew)
    u16*   Wtc    = (u16*)alloc((size_t)256 * 128 * 2);
    u16*   Wtu    = (u16*)alloc((size_t)128 * 256 * 2);
    u16*   X1b    = (u16*)alloc((size_t)n * 128 * 2);   // 12.8e6 B
    u8*    X2q    = (u8*)alloc((size_t)n * 128);        //  6.4e6 B
    u8*    Zq     = (u8*)alloc((size_t)n * 128);        //  6.4e6 B
    u16*   aggb   = (u16*)alloc((size_t)n * 128 * 2);
    int*   bsum   = (int*)alloc(64 * 4);
    int*   boff   = (int*)alloc(64 * 4);
    u32*   segsum = (u32*)alloc((size_t)NSEG * (n / 2) * 4);  // 800 KB, fresh
    // hb16 = NB*(n/2)*4 = 25.6e6 B aliases [X1b|X2q|Zq] (exact, %256==0 each).
    // Lifetime hist..fill; X1b/X2q/Zq written only after k_fill.
    // cva/bsum/boff/segsum NOT aliased (R6 lesson).
    u32*   hb16   = (u32*)X1b;

    int n2 = n / 2;
    int nb = (n + 1023) / 1024;    // 49 <= 64
    int gblks = (n2 + 255) / 256;  // 98

    k_prep<<<256, 256, 0, stream>>>(W1, W2, Wup, Wtc, Wtu);
    k_edge<<<(E + 255) / 256, 256, 0, stream>>>(ea, We1, be1, We2, be2, ew, E);
    k_hist<<<NB, 1024, 0, stream>>>(src, dst, hb16, E, n);
    k_relscan1<<<dim3(gblks, NSEG), 256, 0, stream>>>(hb16, segsum, n2);
    k_relscan2<<<gblks, 256, 0, stream>>>(segsum, tot, n2);
    k_scan_a<<<nb, 256, 0, stream>>>(tot, bsum, n);
    k_scan_b<<<1, 64, 0, stream>>>(bsum, boff, rowptr, nb, n);
    k_scan_c<<<nb, 256, 0, stream>>>(tot, boff, rowptr, n);
    k_fill<<<NB, 1024, 0, stream>>>(src, dst, ew, hb16, segsum, rowptr, cva,
                                    E, n);
    k_deg<<<(n + 3) / 4, 256, 0, stream>>>(rowptr, cva, dinv, n);
    k_gemm1<<<(n + 31) / 32, 256, 0, stream>>>(H, Wtc, dinv, X1b, X2q, n);
    // u = Ar @ X2' ; Z' = gc*X1' + (1-gc)*dinv^2*u   (Z' stored fp8)
    k_spmm<true><<<(n + 3) / 4, 256, 0, stream>>>(rowptr, cva, X2q, X1b,
                                                  (void*)Zq, g, dinv, n);
    // v = Ar @ Z'   (aggb stored bf16)
    k_spmm<false><<<(n + 3) / 4, 256, 0, stream>>>(rowptr, cva, Zq, nullptr,
                                                   (void*)aggb, g, dinv, n);
    k_final<<<(n + 31) / 32, 256, 0, stream>>>(aggb, H, Wtu, bup, dinv, out, n);
}

// Round 15
// 202.150 us; speedup vs baseline: 1.1223x; 1.0051x over previous
//
#include <hip/hip_runtime.h>
#include <stdint.h>

typedef unsigned int u32;
typedef uint8_t u8;
typedef uint16_t u16;
typedef __attribute__((ext_vector_type(8))) short bf16x8;
typedef __attribute__((ext_vector_type(4))) float f32x4;
typedef __attribute__((ext_vector_type(2))) float f32x2v;

#define EPSV 1e-12f
#define NB 256           // histogram blocks (1 per CU)
#define NSEG 8           // relscan segments (NB/NSEG = 32 blocks each)
#define BINS_H 51200     // hist bins/pass (u16 packed, 100KB LDS, 1 pass)
#define BINS_F 51200     // fill bins/pass (u16 packed, 100KB LDS, 1 pass)

#if __has_builtin(__builtin_amdgcn_cvt_pk_f32_fp8) && \
    __has_builtin(__builtin_amdgcn_cvt_pk_fp8_f32)
#define FP8_HW 1
#endif

__device__ __forceinline__ u16 f2bf(float f) {
    u32 u = __float_as_uint(f);
    return (u16)((u + 0x7fffu + ((u >> 16) & 1u)) >> 16);
}
__device__ __forceinline__ float bf2f(u32 s) { return __uint_as_float(s << 16); }

// ---- fp8 e4m3 helpers ------------------------------------------------------
__device__ __forceinline__ float fp8_sw(u32 b) {
    int e = (b >> 3) & 0xf, m = b & 7;
    float v = e ? ldexpf((float)(8 + m), e - 10) : ldexpf((float)m, -9);
    return (b & 0x80) ? -v : v;
}
__device__ __forceinline__ u32 f2fp8_sw(float f) {
    u32 s = (__float_as_uint(f) >> 31) << 7;
    f = fabsf(f);
    if (f >= 448.f) return s | 0x7e;
    if (f < 0x1p-10f) return s;
    int ex; float mant = frexpf(f, &ex);
    int E = ex + 6;
    if (E >= 1) {
        int q = (int)rintf(mant * 16.f);
        if (q == 16) { q = 8; E += 1; }
        if (E > 15) return s | 0x7e;
        return s | ((u32)E << 3) | (u32)(q - 8);
    }
    int q = (int)rintf(f * 512.f);
    if (q > 7) return s | 0x08;
    return s | (u32)q;
}
// word-select operand must be an immediate -> two separate wrappers
__device__ __forceinline__ f32x2v fp8lo(u32 v) {
#ifdef FP8_HW
    return __builtin_amdgcn_cvt_pk_f32_fp8((int)v, false);
#else
    f32x2v r; r.x = fp8_sw(v & 0xff); r.y = fp8_sw((v >> 8) & 0xff);
    return r;
#endif
}
__device__ __forceinline__ f32x2v fp8hi(u32 v) {
#ifdef FP8_HW
    return __builtin_amdgcn_cvt_pk_f32_fp8((int)v, true);
#else
    u32 w = v >> 16;
    f32x2v r; r.x = fp8_sw(w & 0xff); r.y = fp8_sw((w >> 8) & 0xff);
    return r;
#endif
}
__device__ __forceinline__ u32 f2fp8(float f) {
#ifdef FP8_HW
    return (u32)__builtin_amdgcn_cvt_pk_fp8_f32(f, f, 0, false) & 0xffu;
#else
    return f2fp8_sw(f);
#endif
}
__device__ __forceinline__ u32 fp8pack2(float a, float b) {
    return f2fp8(a) | (f2fp8(b) << 8);
}

// ---------------------------------------------------------------------------
// K0: precompute transposed bf16 weights
// ---------------------------------------------------------------------------
__global__ __launch_bounds__(256) void k_prep(
    const float* __restrict__ W1, const float* __restrict__ W2,
    const float* __restrict__ Wup, u16* __restrict__ Wtc,
    u16* __restrict__ Wtu)
{
    int gid = blockIdx.x * 256 + threadIdx.x;
    if (gid < 32768) {
        int c = gid >> 7, k = gid & 127;
        float v = (c < 128) ? W1[k * 128 + c] : W2[k * 128 + (c - 128)];
        Wtc[gid] = f2bf(v);
    } else {
        int g = gid - 32768;      // c*256 + k
        int c = g >> 8, k = g & 255;
        Wtu[g] = f2bf(Wup[k * 128 + c]);
    }
}

// ---------------------------------------------------------------------------
// K1: edge MLP -> sigmoid weights (no atomics)
// ---------------------------------------------------------------------------
__global__ __launch_bounds__(256) void k_edge(
    const float* __restrict__ ea, const float* __restrict__ We1,
    const float* __restrict__ be1, const float* __restrict__ We2,
    const float* __restrict__ be2, float* __restrict__ ew, int E)
{
    __shared__ float w1t[32 * 16];
    __shared__ float b1s[32];
    __shared__ float w2s[32];
    __shared__ float b2s;
    int tid = threadIdx.x;
    for (int i = tid; i < 512; i += 256) {
        int k = i >> 5, j = i & 31;
        w1t[j * 16 + k] = We1[i];
    }
    if (tid < 32) { b1s[tid] = be1[tid]; w2s[tid] = We2[tid]; }
    if (tid == 0) b2s = be2[0];
    __syncthreads();

    int e = blockIdx.x * 256 + tid;
    if (e >= E) return;

    const float4* pa = (const float4*)(ea + (size_t)e * 16);
    float4 A0 = pa[0], A1 = pa[1], A2 = pa[2], A3 = pa[3];
    float av[16] = {A0.x, A0.y, A0.z, A0.w, A1.x, A1.y, A1.z, A1.w,
                    A2.x, A2.y, A2.z, A2.w, A3.x, A3.y, A3.z, A3.w};

    float acc = b2s;
#pragma unroll
    for (int j = 0; j < 32; ++j) {
        const float4* wr = (const float4*)(w1t + j * 16);
        float4 q0 = wr[0], q1 = wr[1], q2 = wr[2], q3 = wr[3];
        float s = b1s[j];
        s += av[0] * q0.x + av[1] * q0.y + av[2] * q0.z + av[3] * q0.w;
        s += av[4] * q1.x + av[5] * q1.y + av[6] * q1.z + av[7] * q1.w;
        s += av[8] * q2.x + av[9] * q2.y + av[10] * q2.z + av[11] * q2.w;
        s += av[12] * q3.x + av[13] * q3.y + av[14] * q3.z + av[15] * q3.w;
        acc += fmaxf(s, 0.f) * w2s[j];
    }
    ew[e] = 1.f / (1.f + __expf(-acc));
}

// ---------------------------------------------------------------------------
// K2: per-block LDS histograms; OUTPUT packed u16 (hb16[b][g] = counts of
//     rows 2g, 2g+1). Per-slice count <= 6250 fits u16. Single pass
//     (BINS_H=51200 >= n, 100KB LDS — gfx950 allows up to 160KB/WG).
// ---------------------------------------------------------------------------
__global__ __launch_bounds__(1024) void k_hist(
    const int* __restrict__ src, const int* __restrict__ dst,
    u32* __restrict__ hb16, int E, int n)
{
    __shared__ u32 h[BINS_H / 2];
    int b = blockIdx.x;
    int n2 = n >> 1;
    int E2 = 2 * E;
    int per = (E2 + NB - 1) / NB;
    int lo_e = b * per, hi_e = min(E2, lo_e + per);
    int npass = (n + BINS_H - 1) / BINS_H;

    for (int pass = 0; pass < npass; ++pass) {
        int lo = pass * BINS_H, hi = min(n, lo + BINS_H);
        for (int i = threadIdx.x; i < BINS_H / 2; i += 1024) h[i] = 0;
        __syncthreads();
        for (int idx = lo_e + threadIdx.x; idx < hi_e; idx += 1024) {
            int r = (idx < E) ? src[idx] : dst[idx - E];
            if (r >= lo && r < hi) {
                int rr = r - lo;
                atomicAdd(&h[rr >> 1], 1u << ((rr & 1) * 16));
            }
        }
        __syncthreads();
        int nw = (hi - lo + 1) >> 1;
        for (int i = threadIdx.x; i < nw; i += 1024)
            hb16[(size_t)b * n2 + (lo >> 1) + i] = h[i];
        __syncthreads();
    }
}

// ---------------------------------------------------------------------------
// K3a: per-SEGMENT in-place packed exclusive prefix (32 blocks each);
//      emits packed segment sums. Grid: (gblks, NSEG).
// ---------------------------------------------------------------------------
__global__ __launch_bounds__(256) void k_relscan1(
    u32* __restrict__ hb16, u32* __restrict__ segsum, int n2)
{
    int g = blockIdx.x * 256 + threadIdx.x;
    if (g >= n2) return;
    int s = blockIdx.y;
    int b0 = s * (NB / NSEG);
    u32 run = 0;
    for (int b = b0; b < b0 + NB / NSEG; ++b) {
        u32 v = hb16[(size_t)b * n2 + g];
        hb16[(size_t)b * n2 + g] = run;
        run += v;                      // no cross-field carry: totals < 2^16
    }
    segsum[(size_t)s * n2 + g] = run;
}

// ---------------------------------------------------------------------------
// K3b: exclusive scan of NSEG segment sums in place (-> segoff); emits tot.
// ---------------------------------------------------------------------------
__global__ __launch_bounds__(256) void k_relscan2(
    u32* __restrict__ segsum, int* __restrict__ tot, int n2)
{
    int g = blockIdx.x * 256 + threadIdx.x;
    if (g >= n2) return;
    u32 run = 0;
#pragma unroll
    for (int s = 0; s < NSEG; ++s) {
        u32 v = segsum[(size_t)s * n2 + g];
        segsum[(size_t)s * n2 + g] = run;
        run += v;
    }
    ((int2*)tot)[g] = make_int2((int)(run & 0xffffu), (int)(run >> 16));
}

// ---------------------------------------------------------------------------
// K4a: chunk sums (1024 elems/block; 256 thr x int4)
// ---------------------------------------------------------------------------
__global__ __launch_bounds__(256) void k_scan_a(
    const int* __restrict__ tot, int* __restrict__ bsum, int n)
{
    int tid = threadIdx.x, b = blockIdx.x;
    int i0 = b * 1024 + tid * 4;
    int s = 0;
    if (i0 + 3 < n) {
        int4 v = *(const int4*)(tot + i0);
        s = v.x + v.y + v.z + v.w;
    } else {
#pragma unroll
        for (int k = 0; k < 4; ++k) if (i0 + k < n) s += tot[i0 + k];
    }
#pragma unroll
    for (int d = 1; d < 64; d <<= 1) s += __shfl_xor(s, d);
    __shared__ int ws[4];
    if ((tid & 63) == 0) ws[tid >> 6] = s;
    __syncthreads();
    if (tid == 0) bsum[b] = ws[0] + ws[1] + ws[2] + ws[3];
}

// ---------------------------------------------------------------------------
// K4b: one-wave exclusive scan of chunk sums (nb <= 64, i.e. n <= 65536);
//      also writes rowptr[n] = grand total.
// ---------------------------------------------------------------------------
__global__ __launch_bounds__(64) void k_scan_b(
    const int* __restrict__ bsum, int* __restrict__ boff,
    int* __restrict__ rowptr, int nb, int n)
{
    int lane = threadIdx.x;
    int v = (lane < nb) ? bsum[lane] : 0;
    int p = v;
#pragma unroll
    for (int d = 1; d < 64; d <<= 1) {
        int t = __shfl_up(p, d);
        if (lane >= d) p += t;
    }
    if (lane < nb) boff[lane] = p - v;     // exclusive
    if (lane == 63) rowptr[n] = p;         // grand total
}

// ---------------------------------------------------------------------------
// K4c: per-chunk exclusive scan + chunk offset -> rowptr[0..n)
// ---------------------------------------------------------------------------
__global__ __launch_bounds__(256) void k_scan_c(
    const int* __restrict__ tot, const int* __restrict__ boff,
    int* __restrict__ rowptr, int n)
{
    int tid = threadIdx.x, b = blockIdx.x;
    int lane = tid & 63, w = tid >> 6;
    int i0 = b * 1024 + tid * 4;
    int v0 = 0, v1 = 0, v2 = 0, v3 = 0;
    if (i0 + 3 < n) {
        int4 t4 = *(const int4*)(tot + i0);
        v0 = t4.x; v1 = t4.y; v2 = t4.z; v3 = t4.w;
    } else {
        if (i0 < n)     v0 = tot[i0];
        if (i0 + 1 < n) v1 = tot[i0 + 1];
        if (i0 + 2 < n) v2 = tot[i0 + 2];
    }
    int t = v0 + v1 + v2 + v3;
    int p = t;
#pragma unroll
    for (int d = 1; d < 64; d <<= 1) {
        int u = __shfl_up(p, d);
        if (lane >= d) p += u;
    }
    int texc = p - t;                      // exclusive within wave
    __shared__ int ws[4];
    if (lane == 63) ws[w] = p;             // wave total
    __syncthreads();
    int woff = 0;
#pragma unroll
    for (int k = 0; k < 4; ++k) woff += (k < w) ? ws[k] : 0;
    int base = boff[b] + woff + texc;
    int e1 = base + v0, e2 = e1 + v1, e3 = e2 + v2;
    if (i0 + 3 < n) {
        *(int4*)(rowptr + i0) = make_int4(base, e1, e2, e3);
    } else {
        if (i0 < n)     rowptr[i0] = base;
        if (i0 + 1 < n) rowptr[i0 + 1] = e1;
        if (i0 + 2 < n) rowptr[i0 + 2] = e2;
    }
}

// ---------------------------------------------------------------------------
// K5: fill CSR. pos = rowptr[r] + u16 relative offset (LDS packed atomic on
//     per-block segment-relative prefix + segment offset, packed add).
//     Single pass (100KB LDS). cva[p] = col<<16 | q16(ew)
// ---------------------------------------------------------------------------
__global__ __launch_bounds__(1024) void k_fill(
    const int* __restrict__ src, const int* __restrict__ dst,
    const float* __restrict__ ew, const u32* __restrict__ hb16,
    const u32* __restrict__ segoff, const int* __restrict__ rowptr,
    u32* __restrict__ cva, int E, int n)
{
    __shared__ u32 rel[BINS_F / 2];
    int b = blockIdx.x;
    int seg = b / (NB / NSEG);
    int n2 = n >> 1;
    int E2 = 2 * E;
    int per = (E2 + NB - 1) / NB;
    int lo_e = b * per, hi_e = min(E2, lo_e + per);
    int npass = (n + BINS_F - 1) / BINS_F;

    for (int pass = 0; pass < npass; ++pass) {
        int lo = pass * BINS_F, hi = min(n, lo + BINS_F);
        int nw = (hi - lo + 1) >> 1;
        for (int i = threadIdx.x; i < nw; i += 1024)
            rel[i] = hb16[(size_t)b * n2 + (lo >> 1) + i] +
                     segoff[(size_t)seg * n2 + (lo >> 1) + i];  // packed add
        __syncthreads();
        for (int idx = lo_e + threadIdx.x; idx < hi_e; idx += 1024) {
            int e = (idx < E) ? idx : idx - E;
            int r, c;
            if (idx < E) { r = src[e]; c = dst[e]; }
            else         { r = dst[e]; c = src[e]; }
            if (r >= lo && r < hi) {
                int rr = r - lo;
                u32 old = atomicAdd(&rel[rr >> 1], 1u << ((rr & 1) * 16));
                int off = (int)((old >> ((rr & 1) * 16)) & 0xffffu);
                u32 q = (u32)rintf(ew[e] * 65535.f);
                cva[rowptr[r] + off] = ((u32)c << 16) | q;
            }
        }
        __syncthreads();
    }
}

// ---------------------------------------------------------------------------
// K6: deg (q16 ew row sums) -> dinv (wave per row)
// ---------------------------------------------------------------------------
__global__ __launch_bounds__(256) void k_deg(
    const int* __restrict__ rowptr, const u32* __restrict__ cva,
    float* __restrict__ dinv, int n)
{
    int lane = threadIdx.x & 63;
    int row = blockIdx.x * 4 + (threadIdx.x >> 6);
    if (row >= n) return;
    int s = rowptr[row], e = rowptr[row + 1];
    float sum = 0.f;
    for (int p = s + lane; p < e; p += 64)
        sum += (float)(cva[p] & 0xffffu);
#pragma unroll
    for (int d = 1; d < 64; d <<= 1) sum += __shfl_xor(sum, d);
    if (lane == 0) dinv[row] = rsqrtf(sum * (1.f / 65535.f) + EPSV);
}

// ---------------------------------------------------------------------------
// K7: gemm1 via MFMA bf16, 32-row tiles. X1' bf16, X2' fp8 e4m3.
// ---------------------------------------------------------------------------
__global__ __launch_bounds__(256) void k_gemm1(
    const float* __restrict__ H, const u16* __restrict__ Wtc,
    const float* __restrict__ dinv, u16* __restrict__ X1b,
    u8* __restrict__ X2q, int n)
{
    __shared__ __align__(16) u16 Asm[32 * 128];
    int tid = threadIdx.x;
    int r0blk = blockIdx.x * 32;
    int wv = tid >> 6, lane = tid & 63;
    int l15 = lane & 15, lg = lane >> 4;
    const u16* Wb = Wtc + (size_t)(wv * 64) * 128;

    bf16x8 bfr[4][4];
#pragma unroll
    for (int ks = 0; ks < 4; ++ks)
#pragma unroll
        for (int nt = 0; nt < 4; ++nt)
            bfr[ks][nt] = *(const bf16x8*)(Wb + (size_t)(nt * 16 + l15) * 128 +
                                           ks * 32 + lg * 8);

#pragma unroll
    for (int it = 0; it < 2; ++it) {
        int sidx = tid + it * 256;           // 32 rows x 16 slots
        int row = sidx >> 4, slot = sidx & 15;
        int gi = r0blk + row;
        float4 f0 = make_float4(0.f, 0.f, 0.f, 0.f), f1 = f0;
        if (gi < n) {
            const float4* p = (const float4*)(H + (size_t)gi * 128 + slot * 8);
            f0 = p[0]; f1 = p[1];
        }
        uint4 w;
        w.x = f2bf(f0.x) | ((u32)f2bf(f0.y) << 16);
        w.y = f2bf(f0.z) | ((u32)f2bf(f0.w) << 16);
        w.z = f2bf(f1.x) | ((u32)f2bf(f1.y) << 16);
        w.w = f2bf(f1.z) | ((u32)f2bf(f1.w) << 16);
        ((uint4*)Asm)[row * 16 + (slot ^ (row & 7))] = w;
    }
    __syncthreads();

    f32x4 acc[2][4] = {};
#pragma unroll
    for (int ks = 0; ks < 4; ++ks) {
        bf16x8 afr[2];
#pragma unroll
        for (int mt = 0; mt < 2; ++mt) {
            int row = mt * 16 + l15;
            int slot = ks * 4 + lg;
            afr[mt] = *(const bf16x8*)(Asm + row * 128 + (slot ^ (row & 7)) * 8);
        }
#pragma unroll
        for (int mt = 0; mt < 2; ++mt)
#pragma unroll
            for (int nt = 0; nt < 4; ++nt)
                acc[mt][nt] = __builtin_amdgcn_mfma_f32_16x16x32_bf16(
                    afr[mt], bfr[ks][nt], acc[mt][nt], 0, 0, 0);
    }

#pragma unroll
    for (int mt = 0; mt < 2; ++mt)
#pragma unroll
        for (int r = 0; r < 4; ++r) {
            int gi = r0blk + mt * 16 + lg * 4 + r;
            if (gi >= n) continue;
            float di = dinv[gi];
#pragma unroll
            for (int nt = 0; nt < 4; ++nt) {
                int col = wv * 64 + nt * 16 + l15;    // wave-uniform branch
                float v = acc[mt][nt][r] * di;
                if (col < 128)
                    X1b[(size_t)gi * 128 + col] = f2bf(v);
                else
                    X2q[(size_t)gi * 128 + (col - 128)] = (u8)f2fp8(v);
            }
        }
}

// ---------------------------------------------------------------------------
// K8: 128-col SpMM over fp8 gather table. Quarter-wave gather, HW fp8 decode.
//   MIX: out(fp8) = gc * Xm[row] + (1-gc)*dinv^2 * (Ar @ Xq)[row]
//  !MIX: out(bf16) = (Ar @ Xq)[row]
// ---------------------------------------------------------------------------
template <bool MIX>
__global__ __launch_bounds__(256) void k_spmm(
    const int* __restrict__ rowptr, const u32* __restrict__ cva,
    const u8* __restrict__ Xq, const u16* __restrict__ Xm,
    void* __restrict__ outp, const float* __restrict__ gp,
    const float* __restrict__ dinv, int n)
{
    int lane = threadIdx.x & 63;
    int q = lane >> 4, l16 = lane & 15;
    int row = blockIdx.x * 4 + (threadIdx.x >> 6);
    if (row >= n) return;
    int s = rowptr[row], e = rowptr[row + 1];
    float a[8] = {0.f, 0.f, 0.f, 0.f, 0.f, 0.f, 0.f, 0.f};

#define GATHER(DD, WW, JJ)                                                   \
    {                                                                        \
        u32 v = __shfl(cv, (JJ));                                            \
        WW = (float)(v & 0xffffu) * (1.f / 65535.f);                         \
        DD = *(const uint2*)(Xq + (size_t)(v >> 16) * 128 + l16 * 8);        \
    }
#define ACC8(DD, WW)                                                         \
    {                                                                        \
        f32x2v p0 = fp8lo(DD.x), p1 = fp8hi(DD.x);                           \
        f32x2v p2 = fp8lo(DD.y), p3 = fp8hi(DD.y);                           \
        a[0] += WW * p0.x; a[1] += WW * p0.y;                                \
        a[2] += WW * p1.x; a[3] += WW * p1.y;                                \
        a[4] += WW * p2.x; a[5] += WW * p2.y;                                \
        a[6] += WW * p3.x; a[7] += WW * p3.y;                                \
    }

    for (int base = s; base < e; base += 64) {
        int p = base + lane;
        u32 cv = (p < e) ? cva[p] : 0u;       // q16=0 -> weight 0
        int m = min(64, e - base);
        for (int j0 = 0; j0 < m; j0 += 16) {
            uint2 d0, d1, d2, d3;
            float w0, w1, w2, w3;
            GATHER(d0, w0, j0 + q)
            GATHER(d1, w1, j0 + 4 + q)
            GATHER(d2, w2, j0 + 8 + q)
            GATHER(d3, w3, j0 + 12 + q)
            ACC8(d0, w0) ACC8(d1, w1) ACC8(d2, w2) ACC8(d3, w3)
        }
    }
#undef GATHER
#undef ACC8

#pragma unroll
    for (int k = 0; k < 8; ++k) {
        a[k] += __shfl_xor(a[k], 16);
        a[k] += __shfl_xor(a[k], 32);
    }
    if (q == 0) {
        if (MIX) {
            float gc = fminf(fmaxf(gp[0], 0.f), 1.f);
            float di = dinv[row];
            float sc = (1.f - gc) * di * di;
            uint4 x1 = *(const uint4*)(Xm + (size_t)row * 128 + l16 * 8);
            a[0] = gc * bf2f(x1.x & 0xffffu) + sc * a[0];
            a[1] = gc * bf2f(x1.x >> 16)     + sc * a[1];
            a[2] = gc * bf2f(x1.y & 0xffffu) + sc * a[2];
            a[3] = gc * bf2f(x1.y >> 16)     + sc * a[3];
            a[4] = gc * bf2f(x1.z & 0xffffu) + sc * a[4];
            a[5] = gc * bf2f(x1.z >> 16)     + sc * a[5];
            a[6] = gc * bf2f(x1.w & 0xffffu) + sc * a[6];
            a[7] = gc * bf2f(x1.w >> 16)     + sc * a[7];
            uint2 o;
            o.x = fp8pack2(a[0], a[1]) | (fp8pack2(a[2], a[3]) << 16);
            o.y = fp8pack2(a[4], a[5]) | (fp8pack2(a[6], a[7]) << 16);
            *(uint2*)((u8*)outp + (size_t)row * 128 + l16 * 8) = o;
        } else {
            uint4 o;
            o.x = f2bf(a[0]) | ((u32)f2bf(a[1]) << 16);
            o.y = f2bf(a[2]) | ((u32)f2bf(a[3]) << 16);
            o.z = f2bf(a[4]) | ((u32)f2bf(a[5]) << 16);
            o.w = f2bf(a[6]) | ((u32)f2bf(a[7]) << 16);
            *(uint4*)((u16*)outp + (size_t)row * 128 + l16 * 8) = o;
        }
    }
}

// ---------------------------------------------------------------------------
// K9: out = relu([dinv⊙agg, H] @ W_up + b_up) via MFMA bf16, 32-row tiles.
// ---------------------------------------------------------------------------
__global__ __launch_bounds__(256) void k_final(
    const u16* __restrict__ aggb, const float* __restrict__ H,
    const u16* __restrict__ Wtu, const float* __restrict__ bup,
    const float* __restrict__ dinv, float* __restrict__ out, int n)
{
    __shared__ __align__(16) u16 Asm[32 * 256];
    int tid = threadIdx.x;
    int r0blk = blockIdx.x * 32;

#pragma unroll
    for (int it = 0; it < 4; ++it) {
        int sidx = tid + it * 256;           // 32 rows x 32 slots
        int row = sidx >> 5, slot = sidx & 31;
        int gi = r0blk + row;
        uint4 w = make_uint4(0u, 0u, 0u, 0u);
        if (gi < n) {
            if (slot < 16) {
                uint4 y = *(const uint4*)(aggb + (size_t)gi * 128 + slot * 8);
                float di = dinv[gi];
                u32 ww[4] = {y.x, y.y, y.z, y.w};
#pragma unroll
                for (int q2 = 0; q2 < 4; ++q2) {
                    float a0 = bf2f(ww[q2] & 0xffffu) * di;
                    float a1 = bf2f(ww[q2] >> 16) * di;
                    ww[q2] = f2bf(a0) | ((u32)f2bf(a1) << 16);
                }
                w = make_uint4(ww[0], ww[1], ww[2], ww[3]);
            } else {
                const float4* p = (const float4*)(H + (size_t)gi * 128 + (slot - 16) * 8);
                float4 f0 = p[0], f1 = p[1];
                w.x = f2bf(f0.x) | ((u32)f2bf(f0.y) << 16);
                w.y = f2bf(f0.z) | ((u32)f2bf(f0.w) << 16);
                w.z = f2bf(f1.x) | ((u32)f2bf(f1.y) << 16);
                w.w = f2bf(f1.z) | ((u32)f2bf(f1.w) << 16);
            }
        }
        int grp = slot >> 3, sub = slot & 7;
        ((uint4*)Asm)[row * 32 + grp * 8 + (sub ^ (row & 7))] = w;
    }
    __syncthreads();

    int wv = tid >> 6, lane = tid & 63;
    int l15 = lane & 15, lg = lane >> 4;
    f32x4 acc[2][2] = {};
    const u16* Wb = Wtu + (size_t)(wv * 32) * 256;

#pragma unroll
    for (int ks = 0; ks < 8; ++ks) {
        bf16x8 bfr[2];
#pragma unroll
        for (int nt = 0; nt < 2; ++nt)
            bfr[nt] = *(const bf16x8*)(Wb + (size_t)(nt * 16 + l15) * 256 +
                                       ks * 32 + lg * 8);
        bf16x8 afr[2];
#pragma unroll
        for (int mt = 0; mt < 2; ++mt) {
            int row = mt * 16 + l15;
            int slot = ks * 4 + lg;
            int grp = slot >> 3, sub = slot & 7;
            afr[mt] = *(const bf16x8*)(Asm + row * 256 +
                                       (grp * 8 + (sub ^ (row & 7))) * 8);
        }
#pragma unroll
        for (int mt = 0; mt < 2; ++mt)
#pragma unroll
            for (int nt = 0; nt < 2; ++nt)
                acc[mt][nt] = __builtin_amdgcn_mfma_f32_16x16x32_bf16(
                    afr[mt], bfr[nt], acc[mt][nt], 0, 0, 0);
    }

#pragma unroll
    for (int mt = 0; mt < 2; ++mt)
#pragma unroll
        for (int r = 0; r < 4; ++r) {
            int gi = r0blk + mt * 16 + lg * 4 + r;
            if (gi >= n) continue;
#pragma unroll
            for (int nt = 0; nt < 2; ++nt) {
                int col = wv * 32 + nt * 16 + l15;
                float v = acc[mt][nt][r] + bup[col];
                out[(size_t)gi * 128 + col] = fmaxf(v, 0.f);
            }
        }
}

// ---------------------------------------------------------------------------
extern "C" void kernel_launch(void* const* d_in, const int* in_sizes, int n_in,
                              void* d_out, int out_size, void* d_ws,
                              size_t ws_size, hipStream_t stream)
{
    (void)n_in; (void)out_size; (void)ws_size;
    const float* H   = (const float*)d_in[0];
    const int*   ei  = (const int*)d_in[1];
    const float* ea  = (const float*)d_in[2];
    const float* W1  = (const float*)d_in[3];
    const float* W2  = (const float*)d_in[4];
    const float* We1 = (const float*)d_in[5];
    const float* be1 = (const float*)d_in[6];
    const float* We2 = (const float*)d_in[7];
    const float* be2 = (const float*)d_in[8];
    const float* g   = (const float*)d_in[9];
    const float* Wup = (const float*)d_in[10];
    const float* bup = (const float*)d_in[11];

    int n = in_sizes[0] / 128;     // 50000 (even; <=65536 for k_scan_b)
    int E = in_sizes[1] / 2;
    const int* src = ei;
    const int* dst = ei + E;
    float* out = (float*)d_out;

    char* wsp = (char*)d_ws;
    auto alloc = [&](size_t bytes) -> char* {
        char* p = wsp;
        wsp += (bytes + 255) & ~(size_t)255;
        return p;
    };
    float* ew     = (float*)alloc((size_t)E * 4);
    int*   tot    = (int*)alloc((size_t)n * 4);
    int*   rowptr = (int*)alloc((size_t)(n + 1) * 4);
    float* dinv   = (float*)alloc((size_t)n * 4);
    u32*   cva    = (u32*)alloc((size_t)2 * E * 4);     // col<<16 | q16(ew)
    u16*   Wtc    = (u16*)alloc((size_t)256 * 128 * 2);
    u16*   Wtu    = (u16*)alloc((size_t)128 * 256 * 2);
    u16*   X1b    = (u16*)alloc((size_t)n * 128 * 2);   // 12.8e6 B
    u8*    X2q    = (u8*)alloc((size_t)n * 128);        //  6.4e6 B
    u8*    Zq     = (u8*)alloc((size_t)n * 128);        //  6.4e6 B
    u16*   aggb   = (u16*)alloc((size_t)n * 128 * 2);
    int*   bsum   = (int*)alloc(64 * 4);
    int*   boff   = (int*)alloc(64 * 4);
    u32*   segsum = (u32*)alloc((size_t)NSEG * (n / 2) * 4);  // 800 KB, fresh
    // hb16 = NB*(n/2)*4 = 25.6e6 B aliases [X1b|X2q|Zq] (exact, %256==0 each).
    // Lifetime hist..fill; X1b/X2q/Zq written only after k_fill.
    // cva/bsum/boff/segsum NOT aliased (R6 lesson).
    u32*   hb16   = (u32*)X1b;

    int n2 = n / 2;
    int nb = (n + 1023) / 1024;    // 49 <= 64
    int gblks = (n2 + 255) / 256;  // 98

    k_prep<<<256, 256, 0, stream>>>(W1, W2, Wup, Wtc, Wtu);
    k_edge<<<(E + 255) / 256, 256, 0, stream>>>(ea, We1, be1, We2, be2, ew, E);
    k_hist<<<NB, 1024, 0, stream>>>(src, dst, hb16, E, n);
    k_relscan1<<<dim3(gblks, NSEG), 256, 0, stream>>>(hb16, segsum, n2);
    k_relscan2<<<gblks, 256, 0, stream>>>(segsum, tot, n2);
    k_scan_a<<<nb, 256, 0, stream>>>(tot, bsum, n);
    k_scan_b<<<1, 64, 0, stream>>>(bsum, boff, rowptr, nb, n);
    k_scan_c<<<nb, 256, 0, stream>>>(tot, boff, rowptr, n);
    k_fill<<<NB, 1024, 0, stream>>>(src, dst, ew, hb16, segsum, rowptr, cva,
                                    E, n);
    k_deg<<<(n + 3) / 4, 256, 0, stream>>>(rowptr, cva, dinv, n);
    k_gemm1<<<(n + 31) / 32, 256, 0, stream>>>(H, Wtc, dinv, X1b, X2q, n);
    // u = Ar @ X2' ; Z' = gc*X1' + (1-gc)*dinv^2*u   (Z' stored fp8)
    k_spmm<true><<<(n + 3) / 4, 256, 0, stream>>>(rowptr, cva, X2q, X1b,
                                                  (void*)Zq, g, dinv, n);
    // v = Ar @ Z'   (aggb stored bf16)
    k_spmm<false><<<(n + 3) / 4, 256, 0, stream>>>(rowptr, cva, Zq, nullptr,
                                                   (void*)aggb, g, dinv, n);
    k_final<<<(n + 31) / 32, 256, 0, stream>>>(aggb, H, Wtu, bup, dinv, out, n);
}